// Round 11
// baseline (138.339 us; speedup 1.0000x reference)
//
#include <hip/hip_runtime.h>
#include <math.h>

#define BB 2
#define TT 512
#define UU 48
#define DD 512
#define HH 1024
#define KK 128

typedef _Float16 f16x8 __attribute__((ext_vector_type(8)));
typedef __fp16 fp16x2_t __attribute__((ext_vector_type(2)));
typedef float floatx4 __attribute__((ext_vector_type(4)));
typedef __attribute__((address_space(3))) _Float16 lds_f16;
typedef __attribute__((address_space(1))) const void g_cvoid;
typedef __attribute__((address_space(3))) void l_void;

// tanh from pre-scaled input z = 2*log2(e)*x (stored f16 by mid):
// tanh(x) = 1 - 2/(2^z + 1). 2 trans + ~5 VALU per 2 elems, +-inf safe.
__device__ __forceinline__ f16x8 tanh8z(f16x8 z) {
    f16x8 o;
#pragma unroll
    for (int i = 0; i < 8; i += 2) {
        float e0 = __builtin_amdgcn_exp2f((float)z[i]);
        float e1 = __builtin_amdgcn_exp2f((float)z[i + 1]);
        float r0 = __builtin_amdgcn_rcpf(e0 + 1.0f);
        float r1 = __builtin_amdgcn_rcpf(e1 + 1.0f);
        fp16x2_t p = __builtin_amdgcn_cvt_pkrtz(fmaf(-2.0f, r0, 1.0f),
                                                fmaf(-2.0f, r1, 1.0f));
        o[i] = (_Float16)p[0];
        o[i + 1] = (_Float16)p[1];
    }
    return o;
}

// ---------------- mid v5r: x4-amplified (IDEMPOTENT) for measurement -------
// Identical math to mid v5; the outer rep-loop re-runs the K-loop 4x (acc
// re-zeroed each rep), stores once. Writes the same bytes as v5 -> correct.
// Purpose: mid has never appeared in rocprof's top-5; at ~4x duration it
// ranks, giving the first direct measurement + counters. Strip next round.
__global__ __launch_bounds__(256) void mid_kernel5r(
    const float* __restrict__ img, const float* __restrict__ labf,
    const float* __restrict__ W1, const float* __restrict__ W2,
    const float* __restrict__ conv_w,
    const float* __restrict__ b1, const float* __restrict__ conv_b,
    const float* __restrict__ masks,
    _Float16* __restrict__ imgHf, _Float16* __restrict__ labHf,
    _Float16* __restrict__ W2s, float* __restrict__ seg_out) {
    int bid = blockIdx.x, tid = threadIdx.x;
    if (bid >= 624) {  // W2 swizzle x4 (idempotent)
        for (int rep = 0; rep < 4; ++rep) {
            int base = (bid - 624) * 256 + tid;
#pragma unroll
            for (int i = 0; i < 32; ++i) {
                int o = base + i * 4096;
                int hg = o >> 10, kk2 = (o >> 3) & 127, hl = o & 7;
                W2s[o] = (_Float16)W2[(size_t)kk2 * HH + hg * 8 + hl];
            }
        }
        return;
    }
    __shared__ __align__(16) _Float16 a_s[32][72];
    __shared__ __align__(16) _Float16 w_s[4096];  // [8 kgroups][64 n][8]
    const float* Arow;
    const float* Wbase;
    int r0, n0b, wstride, region;
    if (bid < 512) {
        region = 0; Arow = img; Wbase = W1 + 512; wstride = 2 * DD;
        int xcd = bid & 7, j = bid >> 3;
        r0 = (j & 31) * 32; n0b = (xcd * 2 + (j >> 5)) * 64;
    } else if (bid < 560) {
        region = 1; Arow = labf; Wbase = W1; wstride = 2 * DD;
        int i = bid - 512; r0 = (i % 3) * 32; n0b = (i / 3) * 64;
    } else {
        region = 2; Arow = img; Wbase = conv_w; wstride = DD;
        int i = bid - 560; r0 = (i >> 1) * 32; n0b = (i & 1) * 64;
    }
    int lane = tid & 63, wv = tid >> 6;
    int m0 = (wv & 1) * 16, n0w = (wv >> 1) * 32;
    int q = lane >> 4, r = lane & 15;
    int arow = tid >> 3, acol = (tid & 7) * 8;
    int wn = tid >> 2, wk0 = (tid & 3) * 16;  // 4 threads per W row, 16 k each
    const float* aptr = &Arow[(size_t)(r0 + arow) * DD + acol];
    const float* wptr = &Wbase[(size_t)(n0b + wn) * wstride + wk0];
    floatx4 acc[2];
    for (int rep = 0; rep < 4; ++rep) {
        acc[0] = (floatx4){0.f, 0.f, 0.f, 0.f};
        acc[1] = (floatx4){0.f, 0.f, 0.f, 0.f};
        float4 pa0, pa1, pw[4];
        pa0 = *(const float4*)aptr;
        pa1 = *(const float4*)(aptr + 4);
#pragma unroll
        for (int i2 = 0; i2 < 4; ++i2) pw[i2] = *(const float4*)(wptr + i2 * 4);
        for (int c = 0; c < 8; ++c) {
            f16x8 av;
            av[0] = (_Float16)pa0.x; av[1] = (_Float16)pa0.y;
            av[2] = (_Float16)pa0.z; av[3] = (_Float16)pa0.w;
            av[4] = (_Float16)pa1.x; av[5] = (_Float16)pa1.y;
            av[6] = (_Float16)pa1.z; av[7] = (_Float16)pa1.w;
            *(f16x8*)&a_s[arow][acol] = av;
            f16x8 w0, w1;
            w0[0] = (_Float16)pw[0].x; w0[1] = (_Float16)pw[0].y;
            w0[2] = (_Float16)pw[0].z; w0[3] = (_Float16)pw[0].w;
            w0[4] = (_Float16)pw[1].x; w0[5] = (_Float16)pw[1].y;
            w0[6] = (_Float16)pw[1].z; w0[7] = (_Float16)pw[1].w;
            w1[0] = (_Float16)pw[2].x; w1[1] = (_Float16)pw[2].y;
            w1[2] = (_Float16)pw[2].z; w1[3] = (_Float16)pw[2].w;
            w1[4] = (_Float16)pw[3].x; w1[5] = (_Float16)pw[3].y;
            w1[6] = (_Float16)pw[3].z; w1[7] = (_Float16)pw[3].w;
            int kg = wk0 >> 3;
            *(f16x8*)&w_s[((kg + 0) * 64 + wn) * 8] = w0;
            *(f16x8*)&w_s[((kg + 1) * 64 + wn) * 8] = w1;
            __syncthreads();
            if (c < 7) {
                int cb = (c + 1) * 64;
                pa0 = *(const float4*)(aptr + cb);
                pa1 = *(const float4*)(aptr + cb + 4);
#pragma unroll
                for (int i2 = 0; i2 < 4; ++i2)
                    pw[i2] = *(const float4*)(wptr + cb + i2 * 4);
            }
#pragma unroll
            for (int kt = 0; kt < 2; ++kt) {
                f16x8 af = *(const f16x8*)&a_s[m0 + r][kt * 32 + q * 8];
#pragma unroll
                for (int nt = 0; nt < 2; ++nt) {
                    f16x8 bf = *(const f16x8*)
                        &w_s[((kt * 4 + q) * 64 + n0w + nt * 16 + r) * 8];
                    acc[nt] = __builtin_amdgcn_mfma_f32_16x16x32_f16(
                        af, bf, acc[nt], 0, 0, 0);
                }
            }
            __syncthreads();
        }
    }
    const float SC = 2.8853900817779268f;  // 2*log2(e): pre-scale for tanh8z
    if (region == 0) {
#pragma unroll
        for (int nt = 0; nt < 2; ++nt) {
            int n = n0b + n0w + nt * 16 + r;
#pragma unroll
            for (int rr = 0; rr < 4; ++rr)
                imgHf[(size_t)(r0 + m0 + 4 * q + rr) * HH + n] =
                    (_Float16)(acc[nt][rr] * SC);
        }
    } else if (region == 1) {
#pragma unroll
        for (int nt = 0; nt < 2; ++nt) {
            int n = n0b + n0w + nt * 16 + r;
            float bv = b1[n];
#pragma unroll
            for (int rr = 0; rr < 4; ++rr)
                labHf[(size_t)(r0 + m0 + 4 * q + rr) * HH + n] =
                    (_Float16)((acc[nt][rr] + bv) * SC);
        }
    } else {
#pragma unroll
        for (int nt = 0; nt < 2; ++nt) {
            int k = n0b + n0w + nt * 16 + r;
            float bv = conv_b[k];
#pragma unroll
            for (int rr = 0; rr < 4; ++rr) {
                int row = r0 + m0 + 4 * q + rr;
                int b = row >> 9, t = row & 511;
                seg_out[((size_t)b * KK + k) * TT + t] =
                    (acc[nt][rr] + bv) * masks[row];
            }
        }
    }
}

// ---------------- joint v15: 3-deep DMA ring, counted vmcnt ----------------
// v13's barrier-free 1-wave structure (1536 blocks x 64 thr, 32 rows =
// 2 u x 16 t, img frags shared) + the T3/T4 fix: 3x8KB LDS ring, chunk c+2
// issued while computing c, s_waitcnt vmcnt(22) (NEVER 0 until tail) -- the
// cross-round invariant was ~2100cyc exposed completion latency per chunk
// at pipeline depth 1 (R7-V4: bare issue->drain = 2130 cyc with no compute).
// Depth 3 covers ~2x chunk-time of latency. Fully unrolled (static ring
// indices, rule #20); sched_barrier(0) after each wait (rule #18).
__global__ __launch_bounds__(64) void joint_kernel15(
    const _Float16* __restrict__ imgHf,  // [B*T][H], pre-scaled 2log2e
    const _Float16* __restrict__ labHf,  // [B*U][H], (.+b1) pre-scaled
    const _Float16* __restrict__ W2s,    // swizzled [(h>>3)][k][h&7]
    const float* __restrict__ b2,
    float* __restrict__ out) {           // [B*U*T][K]
    __shared__ __align__(16) _Float16 w_s[3][4096];  // 3 x 8 KB ring
    int lane = threadIdx.x, bid = blockIdx.x;
    int ql = lane >> 4, r = lane & 15;
    int tg = bid & 31;
    int rest = bid >> 5;             // 0..47
    int up = rest % 24, b = rest / 24;
    int t0 = tg * 16, u0 = up * 2;
    const _Float16* ip  = imgHf + (size_t)(b * TT + t0 + r) * HH + ql * 8;
    const _Float16* l0p = labHf + (size_t)(b * UU + u0) * HH + ql * 8;
    const _Float16* l1p = labHf + (size_t)(b * UU + u0 + 1) * HH + ql * 8;
    floatx4 acc0[8] = {}, acc1[8] = {};
    f16x8 Ai[3], Al0[3], Al1[3];     // A-ring (statically indexed)

    // ISSUE chunk cc into ring slot s: 3 A-loads + 8 W2 DMAs = 11 vmem ops
#define ISSUE(cc, s)                                                         \
    {                                                                        \
        int hb_ = (cc) * 32;                                                 \
        Ai[s]  = *(const f16x8*)(ip + hb_);                                  \
        Al0[s] = *(const f16x8*)(l0p + hb_);                                 \
        Al1[s] = *(const f16x8*)(l1p + hb_);                                 \
        const _Float16* ws_ = W2s + (size_t)(cc) * 4096;                     \
        _Pragma("unroll")                                                    \
        for (int j = 0; j < 8; ++j)                                          \
            __builtin_amdgcn_global_load_lds(                                \
                (g_cvoid*)(ws_ + j * 512 + lane * 8),                        \
                (l_void*)((lds_f16*)&w_s[s][j * 512 + lane * 8]), 16, 0, 0); \
    }

    ISSUE(0, 0);
    ISSUE(1, 1);
#pragma unroll
    for (int c = 0; c < 32; ++c) {
        const int S = c % 3, S2 = (c + 2) % 3;  // constants after unroll
        if (c + 2 < 32) ISSUE(c + 2, S2);
        // counted wait: chunks c+1,c+2 stay in flight (22 ops); c's drained
        if (c < 30)
            asm volatile("s_waitcnt vmcnt(22)" ::: "memory");
        else if (c == 30)
            asm volatile("s_waitcnt vmcnt(11)" ::: "memory");
        else
            asm volatile("s_waitcnt vmcnt(0)" ::: "memory");
        __builtin_amdgcn_sched_barrier(0);
        f16x8 a0 = tanh8z(Ai[S] + Al0[S]);
        f16x8 a1 = tanh8z(Ai[S] + Al1[S]);
#pragma unroll
        for (int nt = 0; nt < 8; ++nt) {  // each bf feeds BOTH m-tiles
            f16x8 bf = *(const f16x8*)
                &w_s[S][ql * 1024 + (nt * 16 + r) * 8];
            acc0[nt] = __builtin_amdgcn_mfma_f32_16x16x32_f16(
                a0, bf, acc0[nt], 0, 0, 0);
            acc1[nt] = __builtin_amdgcn_mfma_f32_16x16x32_f16(
                a1, bf, acc1[nt], 0, 0, 0);
        }
    }
#undef ISSUE
    // epilogue: +b2, in-register log-softmax per m-tile
    float b2v[8];
#pragma unroll
    for (int nt = 0; nt < 8; ++nt) b2v[nt] = b2[nt * 16 + r];
#pragma unroll
    for (int mt = 0; mt < 2; ++mt) {
        int flatbase = (b * UU + u0 + mt) * TT + t0 + 4 * ql;
#pragma unroll
        for (int rr = 0; rr < 4; ++rr) {
            float v[8];
            float mx = -INFINITY;
#pragma unroll
            for (int nt = 0; nt < 8; ++nt) {
                v[nt] = (mt ? acc1[nt][rr] : acc0[nt][rr]) + b2v[nt];
                mx = fmaxf(mx, v[nt]);
            }
            mx = fmaxf(mx, __shfl_xor(mx, 1, 16));
            mx = fmaxf(mx, __shfl_xor(mx, 2, 16));
            mx = fmaxf(mx, __shfl_xor(mx, 4, 16));
            mx = fmaxf(mx, __shfl_xor(mx, 8, 16));
            float s = 0.f;
#pragma unroll
            for (int nt = 0; nt < 8; ++nt) s += __expf(v[nt] - mx);
            s += __shfl_xor(s, 1, 16);
            s += __shfl_xor(s, 2, 16);
            s += __shfl_xor(s, 4, 16);
            s += __shfl_xor(s, 8, 16);
            float lse = mx + __logf(s);
            float* orow = out + (size_t)(flatbase + rr) * KK;
#pragma unroll
            for (int nt = 0; nt < 8; ++nt)
                orow[nt * 16 + r] = v[nt] - lse;
        }
    }
}

extern "C" void kernel_launch(void* const* d_in, const int* in_sizes, int n_in,
                              void* d_out, int out_size, void* d_ws, size_t ws_size,
                              hipStream_t stream) {
    const float* img    = (const float*)d_in[0];
    const float* labf   = (const float*)d_in[1];
    const float* masks  = (const float*)d_in[2];
    const float* W1     = (const float*)d_in[3];
    const float* b1     = (const float*)d_in[4];
    const float* W2     = (const float*)d_in[5];
    const float* b2     = (const float*)d_in[6];
    const float* conv_w = (const float*)d_in[7];
    const float* conv_b = (const float*)d_in[8];
    float* out = (float*)d_out;

    _Float16* base  = (_Float16*)d_ws;
    _Float16* imgHf = base;                    // [1024][1024]
    _Float16* labHf = imgHf + 1024 * 1024;     // [96][1024]
    _Float16* W2s   = labHf + 96 * 1024;       // [H/8][K][8] = 131072

    // measurement round: mid x4-amplified (idempotent) so it finally ranks
    // in rocprof's top-5; joint v15 = 3-deep counted-vmcnt pipeline.
    mid_kernel5r<<<640, 256, 0, stream>>>(img, labf, W1, W2, conv_w,
                                          b1, conv_b, masks,
                                          imgHf, labHf, W2s, out);
    joint_kernel15<<<1536, 64, 0, stream>>>(imgHf, labHf, W2s, b2,
                                            out + (size_t)BB * KK * TT);
}

// Round 12
// 120.556 us; speedup vs baseline: 1.1475x; 1.1475x over previous
//
#include <hip/hip_runtime.h>
#include <math.h>

#define BB 2
#define TT 512
#define UU 48
#define DD 512
#define HH 1024
#define KK 128

typedef _Float16 f16x8 __attribute__((ext_vector_type(8)));
typedef __fp16 fp16x2_t __attribute__((ext_vector_type(2)));
typedef float floatx4 __attribute__((ext_vector_type(4)));

// tanh from pre-scaled input z = 2*log2(e)*x (stored f16 by mid):
// tanh(x) = 1 - 2/(2^z + 1). 2 trans + ~5 VALU per 2 elems, +-inf safe.
__device__ __forceinline__ f16x8 tanh8z(f16x8 z) {
    f16x8 o;
#pragma unroll
    for (int i = 0; i < 8; i += 2) {
        float e0 = __builtin_amdgcn_exp2f((float)z[i]);
        float e1 = __builtin_amdgcn_exp2f((float)z[i + 1]);
        float r0 = __builtin_amdgcn_rcpf(e0 + 1.0f);
        float r1 = __builtin_amdgcn_rcpf(e1 + 1.0f);
        fp16x2_t p = __builtin_amdgcn_cvt_pkrtz(fmaf(-2.0f, r0, 1.0f),
                                                fmaf(-2.0f, r1, 1.0f));
        o[i] = (_Float16)p[0];
        o[i + 1] = (_Float16)p[1];
    }
    return o;
}

// ---------------- mid v5: reverted to the plain version --------------------
__global__ __launch_bounds__(256) void mid_kernel5(
    const float* __restrict__ img, const float* __restrict__ labf,
    const float* __restrict__ W1, const float* __restrict__ W2,
    const float* __restrict__ conv_w,
    const float* __restrict__ b1, const float* __restrict__ conv_b,
    const float* __restrict__ masks,
    _Float16* __restrict__ imgHf, _Float16* __restrict__ labHf,
    _Float16* __restrict__ W2s, float* __restrict__ seg_out) {
    int bid = blockIdx.x, tid = threadIdx.x;
    if (bid >= 624) {  // W2 swizzle: W2s[(h>>3)*1024 + k*8 + (h&7)] = W2[k][h]
        int base = (bid - 624) * 256 + tid;
#pragma unroll
        for (int i = 0; i < 32; ++i) {
            int o = base + i * 4096;
            int hg = o >> 10, kk2 = (o >> 3) & 127, hl = o & 7;
            W2s[o] = (_Float16)W2[(size_t)kk2 * HH + hg * 8 + hl];
        }
        return;
    }
    __shared__ __align__(16) _Float16 a_s[32][72];
    __shared__ __align__(16) _Float16 w_s[4096];  // [8 kgroups][64 n][8]
    const float* Arow;
    const float* Wbase;
    int r0, n0b, wstride, region;
    if (bid < 512) {
        region = 0; Arow = img; Wbase = W1 + 512; wstride = 2 * DD;
        int xcd = bid & 7, j = bid >> 3;
        r0 = (j & 31) * 32; n0b = (xcd * 2 + (j >> 5)) * 64;
    } else if (bid < 560) {
        region = 1; Arow = labf; Wbase = W1; wstride = 2 * DD;
        int i = bid - 512; r0 = (i % 3) * 32; n0b = (i / 3) * 64;
    } else {
        region = 2; Arow = img; Wbase = conv_w; wstride = DD;
        int i = bid - 560; r0 = (i >> 1) * 32; n0b = (i & 1) * 64;
    }
    int lane = tid & 63, wv = tid >> 6;
    int m0 = (wv & 1) * 16, n0w = (wv >> 1) * 32;
    int q = lane >> 4, r = lane & 15;
    int arow = tid >> 3, acol = (tid & 7) * 8;
    int wn = tid >> 2, wk0 = (tid & 3) * 16;  // 4 threads per W row, 16 k each
    const float* aptr = &Arow[(size_t)(r0 + arow) * DD + acol];
    const float* wptr = &Wbase[(size_t)(n0b + wn) * wstride + wk0];
    floatx4 acc[2] = {};
    float4 pa0, pa1, pw[4];
    pa0 = *(const float4*)aptr;
    pa1 = *(const float4*)(aptr + 4);
#pragma unroll
    for (int i2 = 0; i2 < 4; ++i2) pw[i2] = *(const float4*)(wptr + i2 * 4);
    for (int c = 0; c < 8; ++c) {
        f16x8 av;
        av[0] = (_Float16)pa0.x; av[1] = (_Float16)pa0.y;
        av[2] = (_Float16)pa0.z; av[3] = (_Float16)pa0.w;
        av[4] = (_Float16)pa1.x; av[5] = (_Float16)pa1.y;
        av[6] = (_Float16)pa1.z; av[7] = (_Float16)pa1.w;
        *(f16x8*)&a_s[arow][acol] = av;
        f16x8 w0, w1;
        w0[0] = (_Float16)pw[0].x; w0[1] = (_Float16)pw[0].y;
        w0[2] = (_Float16)pw[0].z; w0[3] = (_Float16)pw[0].w;
        w0[4] = (_Float16)pw[1].x; w0[5] = (_Float16)pw[1].y;
        w0[6] = (_Float16)pw[1].z; w0[7] = (_Float16)pw[1].w;
        w1[0] = (_Float16)pw[2].x; w1[1] = (_Float16)pw[2].y;
        w1[2] = (_Float16)pw[2].z; w1[3] = (_Float16)pw[2].w;
        w1[4] = (_Float16)pw[3].x; w1[5] = (_Float16)pw[3].y;
        w1[6] = (_Float16)pw[3].z; w1[7] = (_Float16)pw[3].w;
        int kg = wk0 >> 3;
        *(f16x8*)&w_s[((kg + 0) * 64 + wn) * 8] = w0;
        *(f16x8*)&w_s[((kg + 1) * 64 + wn) * 8] = w1;
        __syncthreads();
        if (c < 7) {
            int cb = (c + 1) * 64;
            pa0 = *(const float4*)(aptr + cb);
            pa1 = *(const float4*)(aptr + cb + 4);
#pragma unroll
            for (int i2 = 0; i2 < 4; ++i2)
                pw[i2] = *(const float4*)(wptr + cb + i2 * 4);
        }
#pragma unroll
        for (int kt = 0; kt < 2; ++kt) {
            f16x8 af = *(const f16x8*)&a_s[m0 + r][kt * 32 + q * 8];
#pragma unroll
            for (int nt = 0; nt < 2; ++nt) {
                f16x8 bf = *(const f16x8*)
                    &w_s[((kt * 4 + q) * 64 + n0w + nt * 16 + r) * 8];
                acc[nt] = __builtin_amdgcn_mfma_f32_16x16x32_f16(
                    af, bf, acc[nt], 0, 0, 0);
            }
        }
        __syncthreads();
    }
    const float SC = 2.8853900817779268f;  // 2*log2(e): pre-scale for tanh8z
    if (region == 0) {
#pragma unroll
        for (int nt = 0; nt < 2; ++nt) {
            int n = n0b + n0w + nt * 16 + r;
#pragma unroll
            for (int rr = 0; rr < 4; ++rr)
                imgHf[(size_t)(r0 + m0 + 4 * q + rr) * HH + n] =
                    (_Float16)(acc[nt][rr] * SC);
        }
    } else if (region == 1) {
#pragma unroll
        for (int nt = 0; nt < 2; ++nt) {
            int n = n0b + n0w + nt * 16 + r;
            float bv = b1[n];
#pragma unroll
            for (int rr = 0; rr < 4; ++rr)
                labHf[(size_t)(r0 + m0 + 4 * q + rr) * HH + n] =
                    (_Float16)((acc[nt][rr] + bv) * SC);
        }
    } else {
#pragma unroll
        for (int nt = 0; nt < 2; ++nt) {
            int k = n0b + n0w + nt * 16 + r;
            float bv = conv_b[k];
#pragma unroll
            for (int rr = 0; rr < 4; ++rr) {
                int row = r0 + m0 + 4 * q + rr;
                int b = row >> 9, t = row & 511;
                seg_out[((size_t)b * KK + k) * TT + t] =
                    (acc[nt][rr] + bv) * masks[row];
            }
        }
    }
}

// ---------------- joint v16: mid-clone (the measured-fast pattern) ---------
// mid runs ~480 cyc/chunk with reg-staged COALESCED loads -> LDS -> MFMA,
// 2 barriers/chunk. Every slow joint loaded A-fragments per-lane row-strided
// (2KB pitch) straight from global. v16 transplants mid's skeleton exactly:
// 768 blocks x 256 thr (4 waves). Block = 64 rows x 128 cols (full N ->
// softmax wave-local, no tanh duplication; wave = 16 rows). 16 chunks of
// 64 h: [store staged regs->LDS] barrier [issue c+1 reg loads] [compute:
// af+lab from LDS, tanh, 16 MFMA] barrier. Single buffer, ~25KB LDS,
// 3 blocks/CU (12 waves). Rolled c-loop (no I-cache blowup, R11 lesson).
__global__ __launch_bounds__(256) void joint_kernel16(
    const _Float16* __restrict__ imgHf,  // [B*T][H], pre-scaled 2log2e
    const _Float16* __restrict__ labHf,  // [B*U][H], (.+b1) pre-scaled
    const _Float16* __restrict__ W2s,    // swizzled [(h>>3)][k][h&7]
    const float* __restrict__ b2,
    float* __restrict__ out) {           // [B*U*T][K]
    __shared__ __align__(16) _Float16 a_s[64][72];  // 9 KB, +8 pad
    __shared__ __align__(16) _Float16 w_s[8192];    // 16 KB: [8 hg][128 k][8]
    __shared__ __align__(16) _Float16 l_s[64];      // lab chunk (128 B)
    int tid = threadIdx.x, bid = blockIdx.x;
    int lane = tid & 63, wv = tid >> 6;
    int ql = lane >> 4, r = lane & 15;
    int g0 = bid * 64;               // block's first flat (b,u,t) row
    int bu = g0 >> 9;                // single u per block (64 | 512)
    int tbase = ((bu >= UU) ? TT : 0) + (g0 & 511);
    // coalesced stage mappings (mid-style): A: 4 thr/row x 32B; W: 64B/thr
    int arow = tid >> 2, acol = (tid & 3) * 16;
    const _Float16* ap = imgHf + (size_t)(tbase + arow) * HH + acol;
    const _Float16* wq = W2s + (size_t)tid * 8;
    const _Float16* lp = labHf + (size_t)bu * HH;
    int m0 = wv * 16;                // wave's rows within block
    floatx4 acc[8] = {};
    f16x8 pa0, pa1, pw0, pw1, pw2, pw3, plab;
    // prologue: chunk 0 -> regs
    pa0 = *(const f16x8*)ap;
    pa1 = *(const f16x8*)(ap + 8);
    pw0 = *(const f16x8*)(wq + 0 * 2048);
    pw1 = *(const f16x8*)(wq + 1 * 2048);
    pw2 = *(const f16x8*)(wq + 2 * 2048);
    pw3 = *(const f16x8*)(wq + 3 * 2048);
    if (tid < 8) plab = *(const f16x8*)(lp + tid * 8);
#pragma unroll 1
    for (int c = 0; c < 16; ++c) {
        // store staged regs -> LDS
        *(f16x8*)&a_s[arow][acol] = pa0;
        *(f16x8*)&a_s[arow][acol + 8] = pa1;
        *(f16x8*)&w_s[tid * 8 + 0 * 2048] = pw0;
        *(f16x8*)&w_s[tid * 8 + 1 * 2048] = pw1;
        *(f16x8*)&w_s[tid * 8 + 2 * 2048] = pw2;
        *(f16x8*)&w_s[tid * 8 + 3 * 2048] = pw3;
        if (tid < 8) *(f16x8*)&l_s[tid * 8] = plab;
        __syncthreads();
        // issue next chunk's loads; they drain during tanh+MFMA below
        if (c < 15) {
            int cb = (c + 1) * 64;
            pa0 = *(const f16x8*)(ap + cb);
            pa1 = *(const f16x8*)(ap + cb + 8);
            const _Float16* wc = wq + (size_t)(c + 1) * 8192;
            pw0 = *(const f16x8*)(wc + 0 * 2048);
            pw1 = *(const f16x8*)(wc + 1 * 2048);
            pw2 = *(const f16x8*)(wc + 2 * 2048);
            pw3 = *(const f16x8*)(wc + 3 * 2048);
            if (tid < 8) plab = *(const f16x8*)(lp + cb + tid * 8);
        }
        // compute: 2 k-steps x (A-frag + lab from LDS, tanh, 8 MFMA)
#pragma unroll
        for (int kt = 0; kt < 2; ++kt) {
            f16x8 af = *(const f16x8*)&a_s[m0 + r][kt * 32 + ql * 8];
            f16x8 lf = *(const f16x8*)&l_s[kt * 32 + ql * 8];
            f16x8 a = tanh8z(af + lf);
#pragma unroll
            for (int nt = 0; nt < 8; ++nt) {
                f16x8 bf = *(const f16x8*)
                    &w_s[((kt * 4 + ql) * 128 + nt * 16 + r) * 8];
                acc[nt] = __builtin_amdgcn_mfma_f32_16x16x32_f16(
                    a, bf, acc[nt], 0, 0, 0);
            }
        }
        __syncthreads();
    }
    // epilogue: +b2, in-register log-softmax (wave owns full 128 cols)
    float b2v[8];
#pragma unroll
    for (int nt = 0; nt < 8; ++nt) b2v[nt] = b2[nt * 16 + r];
#pragma unroll
    for (int rr = 0; rr < 4; ++rr) {
        float v[8];
        float mx = -INFINITY;
#pragma unroll
        for (int nt = 0; nt < 8; ++nt) {
            v[nt] = acc[nt][rr] + b2v[nt];
            mx = fmaxf(mx, v[nt]);
        }
        mx = fmaxf(mx, __shfl_xor(mx, 1, 16));
        mx = fmaxf(mx, __shfl_xor(mx, 2, 16));
        mx = fmaxf(mx, __shfl_xor(mx, 4, 16));
        mx = fmaxf(mx, __shfl_xor(mx, 8, 16));
        float s = 0.f;
#pragma unroll
        for (int nt = 0; nt < 8; ++nt) s += __expf(v[nt] - mx);
        s += __shfl_xor(s, 1, 16);
        s += __shfl_xor(s, 2, 16);
        s += __shfl_xor(s, 4, 16);
        s += __shfl_xor(s, 8, 16);
        float lse = mx + __logf(s);
        float* orow = out + (size_t)(g0 + m0 + 4 * ql + rr) * KK;
#pragma unroll
        for (int nt = 0; nt < 8; ++nt)
            orow[nt * 16 + r] = v[nt] - lse;
    }
}

extern "C" void kernel_launch(void* const* d_in, const int* in_sizes, int n_in,
                              void* d_out, int out_size, void* d_ws, size_t ws_size,
                              hipStream_t stream) {
    const float* img    = (const float*)d_in[0];
    const float* labf   = (const float*)d_in[1];
    const float* masks  = (const float*)d_in[2];
    const float* W1     = (const float*)d_in[3];
    const float* b1     = (const float*)d_in[4];
    const float* W2     = (const float*)d_in[5];
    const float* b2     = (const float*)d_in[6];
    const float* conv_w = (const float*)d_in[7];
    const float* conv_b = (const float*)d_in[8];
    float* out = (float*)d_out;

    _Float16* base  = (_Float16*)d_ws;
    _Float16* imgHf = base;                    // [1024][1024]
    _Float16* labHf = imgHf + 1024 * 1024;     // [96][1024]
    _Float16* W2s   = labHf + 96 * 1024;       // [H/8][K][8] = 131072

    mid_kernel5<<<640, 256, 0, stream>>>(img, labf, W1, W2, conv_w,
                                         b1, conv_b, masks,
                                         imgHf, labHf, W2s, out);
    joint_kernel16<<<768, 256, 0, stream>>>(imgHf, labHf, W2s, b2,
                                            out + (size_t)BB * KK * TT);
}